// Round 4
// baseline (425.019 us; speedup 1.0000x reference)
//
#include <hip/hip_runtime.h>
#include <climits>
#include <cstdint>

#define L 1000        // NUM_LABELS
#define NROWS 32768   // 64*512

// ws layout (int32 units):
//   [0,    1000)   first_row[label]  (INT_MAX if unseen)
//   [1024, 2048)   evt_g[rank] = (lab<<10)|m   -- compacted, rank-indexed
//   [2048, 3048)   perm_g[pos]

__global__ void k_init(int* __restrict__ first_row) {
    int i = blockIdx.x * blockDim.x + threadIdx.x;
    if (i < L) first_row[i] = INT_MAX;
}

__global__ void k_first(const int* __restrict__ labels, int* __restrict__ first_row) {
    int i = blockIdx.x * blockDim.x + threadIdx.x;
    if (i < NROWS) atomicMin(&first_row[labels[i]], i);
}

// One block per label: argmax of the first-occurrence row (first-index tiebreak)
// AND the event's rank = #{labels with smaller first_row}. Writes evt_g
// directly compacted in row order.
__global__ void k_argmax(const float* __restrict__ flat, const int* __restrict__ first_row,
                         int* __restrict__ evt_g) {
    int lab = blockIdx.x;
    int row = first_row[lab];
    if (row >= NROWS) return;                 // label absent (block-uniform)
    const float* y = flat + (size_t)row * L;
    int tid = threadIdx.x;
    float bv = -INFINITY;
    int bk = 0x7fffffff;
    for (int k = tid; k < L; k += 256) {
        float v = y[k];
        if (v > bv) { bv = v; bk = k; }       // ascending k => strict > keeps first
    }
    int cnt = 0;                              // rank partial (first_row is L2-hot)
    for (int j = tid; j < L; j += 256) cnt += (first_row[j] < row) ? 1 : 0;
    __shared__ float sv[256];
    __shared__ int   sk[256];
    __shared__ int   sc[256];
    sv[tid] = bv; sk[tid] = bk; sc[tid] = cnt;
    __syncthreads();
    for (int off = 128; off > 0; off >>= 1) {
        if (tid < off) {
            float v2 = sv[tid + off]; int k2 = sk[tid + off];
            if (v2 > sv[tid] || (v2 == sv[tid] && k2 < sk[tid])) { sv[tid] = v2; sk[tid] = k2; }
            sc[tid] += sc[tid + off];
        }
        __syncthreads();
    }
    if (tid == 0) evt_g[sc[0]] = (lab << 10) | sk[0];
}

// Single block. Out-of-order serial replay on thread 0.
//
// Event j: (m_j, l_j). sigma_{-1}=id. r_j = s[m_j]; Plab_j = s[l_j];
// pr_j = s[r_j]; update: swap entries at r_j, l_j.
//
// Issue schedule at iter j (DS ops complete in program order):
//   S1  W_r(j):   pos[r_j] = Plab_j           (operands finalized iter j-1)
//   S2  W_l(j-1): pos[l_{j-1}] = pr_{j-1}, SUPPRESSED (-> dummy slot) when
//       l_{j-1}==r_j (a semantically-later r-write already landed there).
//       Operand = pr materialized from a 2-iter-old read -> no stall.
//   S3  A/B reads for event j+3 (addresses from evt prefetch).
//   S4  finalize event j+1 from 2-iter-old reads a1/b1, patched vs the 5
//       missing writes {l_{j-2}, r_{j-1}, l_{j-1}, r_j, l_j} in semantic
//       order (b-chain: only r-keys; labels are distinct). The l_j key's
//       operand is in flight -> RARE real branch (asm volatile blocks
//       if-conversion so the common path never waits on it).
//   S5  raw pr-read pos[r_{j+1}] (sees S1/S2; misses only l_j's write,
//       fixed by the recurrence pr_j = (r_j==l_{j-1}) ? pr_{j-1} : raw_j,
//       materialized one iter late so it only touches 2-iter-old reads).
//   S6  evt prefetch (3-deep).
// Epilogue: the one still-pending W_l(K-1) (no suppression: no later event).
// Common-path critical chain: pure ALU (~9 cmp + 9 cndmask), no LDS latency
// exposed -> ~60-70 cy/iter vs ~145 before (write-stall + 1-deep reads).
__global__ void __launch_bounds__(1024) k_seq(const int* __restrict__ first_row,
                                              const int* __restrict__ evt_g,
                                              int* __restrict__ perm_g) {
    __shared__ int evt[1008];
    __shared__ int pos[1024];                 // [1000..1023] scratch; 1016 = dummy sink
    int tid = threadIdx.x;
    int present = (tid < L) && (first_row[tid] < NROWS);
    int K = __syncthreads_count(present);     // #events == #present labels
    if (tid < K) evt[tid] = evt_g[tid];
    if (tid >= K && tid < K + 7) evt[tid] = 0;   // pads (m=l=0): read-only, never written back
    if (tid < L) pos[tid] = tid;              // pos = idx_sel^{-1}, initially identity
    __syncthreads();
    if (tid == 0 && K > 0) {
        int e0 = evt[0], e1 = evt[1], e2 = evt[2];
        int r0 = e0 & 1023, l0 = e0 >> 10;    // event j=0 (identity state)
        int Pl0 = l0, praw = r0;              // Plab_0 = l_0, raw pr_0 = m_0
        int rq = 1017, lq = 1016, Plq = 0;    // event j-1 dummies (never match keys)
        int lqq = 1018, Mprev = 0, praw_q = 0;// event j-2 dummies
        int m1 = e1 & 1023, l1 = e1 >> 10, a1 = m1, b1 = l1;  // identity reads
        int m2 = e2 & 1023, l2 = e2 >> 10, a2 = m2, b2 = l2;
        int w3 = evt[3], w4 = evt[4];
        for (int i = 0; i < K; i++) {
            pos[r0] = Pl0;                                   // S1: W_r(j)
            int Mcur = (rq == lqq) ? Mprev : praw_q;         // pr_{j-1} materialized
            int waddr = (lq == r0) ? 1016 : lq;              // S2: W_l(j-1), suppressed
            pos[waddr] = Mcur;
            int m3 = w3 & 1023, l3 = w3 >> 10;               // S3: reads for event j+3
            int a3 = pos[m3];
            int b3 = pos[l3];
            // S4: finalize event j+1 (patch chain in semantic write order)
            int r1f = (m1 == lqq) ? Mprev : a1;              // key l_{j-2} -> pr_{j-2}
            r1f = (m1 == rq) ? Plq : r1f;                    // key r_{j-1} -> Plab_{j-1}
            r1f = (m1 == lq) ? Mcur : r1f;                   // key l_{j-1} -> pr_{j-1}
            r1f = (m1 == r0) ? Pl0 : r1f;                    // key r_j -> Plab_j
            if (m1 == l0) {                                  // key l_j -> pr_j (RARE)
                asm volatile("" ::: "memory");               // force a real branch
                r1f = (r0 == lq) ? Mcur : praw;              // pr_j (may wait: rare only)
            }
            int Pl1f = (l1 == rq) ? Plq : b1;                // b-chain: r-keys only
            Pl1f = (l1 == r0) ? Pl0 : Pl1f;                  // (l/l keys impossible)
            int prawn = pos[r1f];                            // S5: raw pr_{j+1}
            int wn = evt[i + 5];                             // S6: evt prefetch
            // rotate
            Mprev = Mcur; praw_q = praw;
            lqq = lq; rq = r0; Plq = Pl0; lq = l0;
            r0 = r1f; l0 = l1; Pl0 = Pl1f; praw = prawn;
            m1 = m2; l1 = l2; a1 = a2; b1 = b2;
            m2 = m3; l2 = l3; a2 = a3; b2 = b3;
            w3 = w4; w4 = wn;
        }
        int Mfin = (rq == lqq) ? Mprev : praw_q;             // pr_{K-1}
        pos[lq] = Mfin;                                      // final pending W_l(K-1)
    }
    __syncthreads();
    if (tid < L) perm_g[pos[tid]] = tid;      // invert: perm[pos[v]] = v
}

// 4 rows per block IN PARALLEL (four 256-thread groups sharing the p table).
// Global read and write fully coalesced float4; permuted gather goes via LDS.
__global__ void __launch_bounds__(1024) k_gather(const float* __restrict__ flat,
                                                 const int* __restrict__ perm_g,
                                                 float* __restrict__ out) {
    __shared__ __align__(16) int   p[1024];
    __shared__ __align__(16) float buf[4][L];
    int tid = threadIdx.x;
    if (tid < L) p[tid] = perm_g[tid];
    int g = tid >> 8;            // group 0..3 -> row within block
    int t = tid & 255;           // lane-in-group
    size_t row = (size_t)blockIdx.x * 4 + g;
    const float* src = flat + row * L;
    float*       dst = out  + row * L;
    float4 v;
    if (t < 250) v = ((const float4*)src)[t];
    __syncthreads();             // p visible; (v still in flight is fine)
    if (t < 250) ((float4*)buf[g])[t] = v;
    __syncthreads();             // buf visible
    if (t < 250) {
        int j = t * 4;
        float4 o;
        o.x = buf[g][p[j + 0]];
        o.y = buf[g][p[j + 1]];
        o.z = buf[g][p[j + 2]];
        o.w = buf[g][p[j + 3]];
        ((float4*)dst)[t] = o;
    }
}

extern "C" void kernel_launch(void* const* d_in, const int* in_sizes, int n_in,
                              void* d_out, int out_size, void* d_ws, size_t ws_size,
                              hipStream_t stream) {
    const float* flat   = (const float*)d_in[0];   // (64,512,1000) fp32
    const int*   labels = (const int*)d_in[1];     // (64,512) int32
    float* out = (float*)d_out;
    int* ws = (int*)d_ws;
    int* first_row = ws;          // 1000
    int* evt_g     = ws + 1024;   // 1000 (rank-compacted events)
    int* perm_g    = ws + 2048;   // 1000

    k_init  <<<(L + 255) / 256, 256, 0, stream>>>(first_row);
    k_first <<<(NROWS + 255) / 256, 256, 0, stream>>>(labels, first_row);
    k_argmax<<<L, 256, 0, stream>>>(flat, first_row, evt_g);
    k_seq   <<<1, 1024, 0, stream>>>(first_row, evt_g, perm_g);
    k_gather<<<NROWS / 4, 1024, 0, stream>>>(flat, perm_g, out);
}